// Round 2
// baseline (565.052 us; speedup 1.0000x reference)
//
#include <hip/hip_runtime.h>

namespace {
constexpr int kB = 64;
constexpr int kN = 8400;
constexpr int kMain = 8192;          // bitonic-sorted main segment per image
constexpr int kTail = kN - kMain;    // 208, sorted in mergeT_k
constexpr int kReg = 64;
constexpr int kCls = 80;
constexpr int kStride = kReg + kCls; // 144
constexpr int kMaxOut = 100;
constexpr int kM2 = 8704;            // 17 * 512 merged stream length
constexpr float kScoreTh = 0.3f;
constexpr float kIouTh = 0.5f;
}

// ---------------------------------------------------------------------------
// Stage 1: coalesced decode (verified absmax 0.0). UNCHANGED.
// ---------------------------------------------------------------------------
__global__ __launch_bounds__(256) void decode2_k(
    const float* __restrict__ preds,
    const float* __restrict__ anchors,
    float4* __restrict__ boxes,
    float* __restrict__ scores,
    int* __restrict__ labels,
    unsigned long long* __restrict__ keys)
{
    __shared__ float lds[64 * 148];
    const int tid = threadIdx.x;
    const size_t gbase = (size_t)blockIdx.x * 64;

    const float4* src = (const float4*)(preds + gbase * kStride);
    float4* l4 = (float4*)lds;
#pragma unroll
    for (int k = 0; k < 9; ++k) {
        int i = tid + k * 256;
        int row = i / 36, col = i - row * 36;
        l4[row * 37 + col] = src[i];
    }
    __syncthreads();

    const int a = tid >> 2, s = tid & 3;
    const float* rowp = lds + a * 148;

    float x[16];
    const float4* q = (const float4*)(rowp + s * 16);
#pragma unroll
    for (int j = 0; j < 4; ++j) ((float4*)x)[j] = q[j];
    float m = x[0];
#pragma unroll
    for (int j = 1; j < 16; ++j) m = fmaxf(m, x[j]);
    float se = 0.f, we = 0.f;
#pragma unroll
    for (int j = 0; j < 16; ++j) {
        float t = expf(x[j] - m);
        se += t;
        we += t * (float)j;
    }
    float d = we / se;

    const float4* cl = (const float4*)(rowp + kReg + s * 20);
    float bv = -3e38f; int bi = 0;
#pragma unroll
    for (int c = 0; c < 5; ++c) {
        float4 v = cl[c];
        int cb = s * 20 + 4 * c;
        if (v.x > bv) { bv = v.x; bi = cb; }
        if (v.y > bv) { bv = v.y; bi = cb + 1; }
        if (v.z > bv) { bv = v.z; bi = cb + 2; }
        if (v.w > bv) { bv = v.w; bi = cb + 3; }
    }

    const int lane = tid & 63;
    const int base = lane & ~3;
    float d0 = __shfl(d, base + 0, 64);
    float d1 = __shfl(d, base + 1, 64);
    float d2 = __shfl(d, base + 2, 64);
    float d3 = __shfl(d, base + 3, 64);
    float v1 = __shfl(bv, base + 1, 64); int i1 = __shfl(bi, base + 1, 64);
    float v2 = __shfl(bv, base + 2, 64); int i2 = __shfl(bi, base + 2, 64);
    float v3 = __shfl(bv, base + 3, 64); int i3 = __shfl(bi, base + 3, 64);

    if (s == 0) {
        float best = bv; int bl = bi;
        if (v1 > best) { best = v1; bl = i1; }
        if (v2 > best) { best = v2; bl = i2; }
        if (v3 > best) { best = v3; bl = i3; }

        size_t gi = gbase + a;
        int bimg = (int)(gi / kN);
        int n = (int)(gi - (size_t)bimg * kN);
        float4 av = ((const float4*)anchors)[n];
        float ah0 = av.z - av.x, ah1 = av.w - av.y;
        float c0 = (av.x + av.z) * 0.5f, c1 = (av.y + av.w) * 0.5f;
        float bc0 = (d2 - d0) * 0.5f * ah0 + c0;
        float bc1 = (d3 - d1) * 0.5f * ah1 + c1;
        float bh0 = (d2 + d0) * ah0;
        float bh1 = (d3 + d1) * ah1;
        boxes[gi] = make_float4(bc0 - bh0 * 0.5f, bc1 - bh1 * 0.5f,
                                bc0 + bh0 * 0.5f, bc1 + bh1 * 0.5f);
        scores[gi] = best;
        labels[gi] = bl;

        unsigned long long kkey = ~0ULL;
        if (best > kScoreTh) {
            unsigned u = __float_as_uint(best);
            unsigned o = u ^ ((u & 0x80000000u) ? 0xFFFFFFFFu : 0x80000000u);
            kkey = ((unsigned long long)(~o) << 32) | (unsigned)n;
        }
        keys[((size_t)bimg << 14) + n] = kkey;
    }
}

// ---------------------------------------------------------------------------
// Sort pipeline — same comparator network as the verified single-block sort
// (desc = (global_i & size) != 0, sizes 2..8192), split for CU saturation.
//   sortL_k : 256 blocks, 2048-segments, sizes 2..2048 in LDS.
//   lm4_k   : 128 blocks, 4096-halves, strides 2048..1 (size 4096).
//   lm8f_k  : 128 blocks, fused size-8192: stride-4096 min/max of both halves
//             + strides 2048..1 asc; writes to keysM (separate dest = no race).
// ---------------------------------------------------------------------------
__global__ __launch_bounds__(512) void sortL_k(unsigned long long* __restrict__ keys)
{
    __shared__ unsigned long long lk[2048];          // 16 KB
    const int img = blockIdx.x >> 2, seg = blockIdx.x & 3;
    const int gofs = seg << 11;
    unsigned long long* base = keys + ((size_t)img << 14) + gofs;

    for (int t = threadIdx.x; t < 2048; t += 512) lk[t] = base[t];
    __syncthreads();
    for (int size = 2; size <= 2048; size <<= 1) {
        for (int stride = size >> 1; stride > 0; stride >>= 1) {
#pragma unroll
            for (int p = 0; p < 2; ++p) {
                int n = threadIdx.x + (p << 9);
                int i = ((n & ~(stride - 1)) << 1) | (n & (stride - 1));
                int j = i + stride;
                bool desc = ((gofs + i) & size) != 0;
                unsigned long long a = lk[i], c = lk[j];
                bool sw = desc ? (c > a) : (a > c);
                if (sw) { lk[i] = c; lk[j] = a; }
            }
            __syncthreads();
        }
    }
    for (int t = threadIdx.x; t < 2048; t += 512) base[t] = lk[t];
}

__global__ __launch_bounds__(512) void lm4_k(unsigned long long* __restrict__ keys)
{
    __shared__ unsigned long long lk[4096];          // 32 KB
    const int img = blockIdx.x >> 1, half = blockIdx.x & 1;
    const int gofs = half << 12;
    unsigned long long* base = keys + ((size_t)img << 14) + gofs;

    for (int t = threadIdx.x; t < 4096; t += 512) lk[t] = base[t];
    __syncthreads();
    const bool desc = (gofs & 4096) != 0;            // half0 asc, half1 desc
    for (int stride = 2048; stride > 0; stride >>= 1) {
#pragma unroll
        for (int p = 0; p < 4; ++p) {
            int n = threadIdx.x + (p << 9);
            int i = ((n & ~(stride - 1)) << 1) | (n & (stride - 1));
            int j = i + stride;
            unsigned long long a = lk[i], c = lk[j];
            bool sw = desc ? (c > a) : (a > c);
            if (sw) { lk[i] = c; lk[j] = a; }
        }
        __syncthreads();
    }
    for (int t = threadIdx.x; t < 4096; t += 512) base[t] = lk[t];
}

__global__ __launch_bounds__(512) void lm8f_k(
    const unsigned long long* __restrict__ keys,
    unsigned long long* __restrict__ keysM)
{
    __shared__ unsigned long long lk[4096];          // 32 KB
    const int img = blockIdx.x >> 1, half = blockIdx.x & 1;
    const unsigned long long* base = keys + ((size_t)img << 14);

    // size=8192 / stride=4096 pass (ascending everywhere): half0 keeps min,
    // half1 keeps max. Reads only lm4 output; writes only keysM.
    for (int t = threadIdx.x; t < 4096; t += 512) {
        unsigned long long a = base[t], c = base[t + 4096];
        lk[t] = half ? (a > c ? a : c) : (a > c ? c : a);
    }
    __syncthreads();
    for (int stride = 2048; stride > 0; stride >>= 1) {   // ascending merge
#pragma unroll
        for (int p = 0; p < 4; ++p) {
            int n = threadIdx.x + (p << 9);
            int i = ((n & ~(stride - 1)) << 1) | (n & (stride - 1));
            int j = i + stride;
            unsigned long long a = lk[i], c = lk[j];
            if (a > c) { lk[i] = c; lk[j] = a; }
        }
        __syncthreads();
    }
    unsigned long long* dst = keysM + ((size_t)img << 13) + ((size_t)half << 12);
    for (int t = threadIdx.x; t < 4096; t += 512) dst[t] = lk[t];
}

// ---------------------------------------------------------------------------
// mergeT: sort the 208-tail (pad 256) in LDS, then merge-path merge with the
// 8192 ascending main into a fully-sorted 8704 stream (pads ~0ULL at end).
// A-first tie rule = old nms rule (A idx < 8192 <= B idx; real keys unique).
// ---------------------------------------------------------------------------
__global__ __launch_bounds__(512) void mergeT_k(
    const unsigned long long* __restrict__ keysM,
    const unsigned long long* __restrict__ keys,
    unsigned long long* __restrict__ keys2)
{
    __shared__ unsigned long long tailL[256];
    const int b = blockIdx.x, tid = threadIdx.x;
    const unsigned long long* A = keysM + ((size_t)b << 13);
    unsigned long long* dst = keys2 + (size_t)b * kM2;

    if (tid < 256)
        tailL[tid] = (tid < kTail) ? keys[((size_t)b << 14) + kMain + tid] : ~0ULL;
    __syncthreads();
    for (int size = 2; size <= 256; size <<= 1) {
        for (int stride = size >> 1; stride > 0; stride >>= 1) {
            if (tid < 128) {
                int i = ((tid & ~(stride - 1)) << 1) | (tid & (stride - 1));
                int j = i + stride;
                bool desc = (i & size) != 0;
                unsigned long long a = tailL[i], c = tailL[j];
                bool sw = desc ? (c > a) : (a > c);
                if (sw) { tailL[i] = c; tailL[j] = a; }
            }
            __syncthreads();
        }
    }

    // thread t emits merged diagonals [t*17, t*17+17)
    const int d0 = tid * 17;
    int lo = d0 - 256; lo = lo < 0 ? 0 : (lo > kMain ? kMain : lo);
    int hi = d0 > kMain ? kMain : d0;
    while (lo < hi) {
        int mid = (lo + hi) >> 1;
        if (tailL[d0 - mid - 1] < A[mid]) hi = mid; else lo = mid + 1;
    }
    int ai = lo, bi = d0 - lo;
#pragma unroll
    for (int k = 0; k < 17; ++k) {
        unsigned long long av = (ai < kMain) ? A[ai] : ~0ULL;
        unsigned long long bv = (bi < 256) ? tailL[bi] : ~0ULL;
        unsigned long long v;
        if (av <= bv) { v = av; ++ai; } else { v = bv; ++bi; }
        dst[d0 + k] = v;
    }
}

// ---------------------------------------------------------------------------
// Stage 2: greedy NMS over the fully-sorted stream. 512-candidate chunks,
// no merge-path, 2 barriers/chunk. Resolve: lane-major packing -> each
// wave0 lane owns 8 consecutive candidates (one ballot-byte); find-first =
// 1 ballot + 1 shfl; sbox at stride-9 float4 (b128 bank floor).
// ---------------------------------------------------------------------------
__global__ __launch_bounds__(512) void nms_k(
    const float4* __restrict__ boxes,
    const float* __restrict__ scores,
    const int* __restrict__ labels,
    const unsigned long long* __restrict__ keys2,
    float* __restrict__ out)
{
    __shared__ float4 sboxT[576];
    __shared__ float  sarT[576];
    __shared__ int    sidxT[576];
    __shared__ float4 kboxL[kMaxOut];
    __shared__ float  kareaL[kMaxOut];
    __shared__ int    kidxL[kMaxOut];
    __shared__ unsigned long long ballS[8];
    __shared__ int kcS, doneS, stopS;

    const int b = blockIdx.x, tid = threadIdx.x;
    const unsigned long long* src = keys2 + (size_t)b * kM2;
    const float4* bx = boxes + (size_t)b * kN;

    if (tid == 0) { kcS = 0; doneS = 0; }

    int kc = 0;
    for (int c = 0; c < 17; ++c) {
        unsigned long long key = src[(c << 9) + tid];
        bool alive = (key != ~0ULL);
        int idx = alive ? (int)(key & 0xFFFFFFFFULL) : 0;
        float4 cb = bx[idx];
        float ac = (cb.z - cb.x) * (cb.w - cb.y);

        // pre-test vs keeps from previous chunks (kboxL[0..kc) stable:
        // resolve only appends at >= kc, so no race with this read)
        if (alive) {
            for (int k = 0; k < kc; ++k) {
                float4 kb = kboxL[k];
                float t0 = fmaxf(kb.x, cb.x), t1 = fmaxf(kb.y, cb.y);
                float b0 = fminf(kb.z, cb.z), b1 = fminf(kb.w, cb.w);
                float inter = fmaxf(b0 - t0, 0.f) * fmaxf(b1 - t1, 0.f);
                float iou = inter / (kareaL[k] + ac - inter + 1e-9f);
                if (iou > kIouTh) { alive = false; break; }
            }
        }
        const int sl = ((tid >> 3) * 9) + (tid & 7);   // candidate c=tid -> [c>>3][c&7]
        sboxT[sl] = cb; sarT[sl] = ac; sidxT[sl] = idx;
        unsigned long long mm = __ballot((int)alive);
        if ((tid & 63) == 0) ballS[tid >> 6] = mm;
        if (tid == 0) stopS = (key == ~0ULL);          // sorted: pad => all done
        __syncthreads();                               // B2
        if (stopS) break;

        // ---- wave0-only in-chunk greedy resolve ----
        if (tid < 64) {
            const int l = tid;
            // bits j of a8 = candidates c = 8l..8l+7 (byte (l&7) of ballS[l>>3])
            unsigned a8 = (unsigned)((ballS[l >> 3] >> ((l & 7) << 3)) & 0xFFULL);
            int kcl = kc;
            while (true) {
                unsigned long long m = __ballot(a8 != 0);
                if (!m) break;
                int lf = __ffsll(m) - 1;
                unsigned af = (unsigned)__shfl((int)a8, lf, 64);
                int jf = __ffs((int)af) - 1;           // smallest candidate = (lf,jf)
                int ks = lf * 9 + jf;
                float4 kb = sboxT[ks];                 // broadcast
                float kar = sarT[ks];
                if (l == 0) { kboxL[kcl] = kb; kareaL[kcl] = kar; kidxL[kcl] = sidxT[ks]; }
                if (l == lf) a8 &= ~(1u << jf);
                ++kcl;
                if (kcl == kMaxOut) break;
#pragma unroll
                for (int j = 0; j < 8; ++j) {
                    if ((a8 >> j) & 1u) {
                        int sj = l * 9 + j;
                        float4 cb2 = sboxT[sj];
                        float ac2 = sarT[sj];
                        float t0 = fmaxf(kb.x, cb2.x), t1 = fmaxf(kb.y, cb2.y);
                        float b0 = fminf(kb.z, cb2.z), b1 = fminf(kb.w, cb2.w);
                        float inter = fmaxf(b0 - t0, 0.f) * fmaxf(b1 - t1, 0.f);
                        float iou = inter / (kar + ac2 - inter + 1e-9f);
                        if (iou > kIouTh) a8 &= ~(1u << j);
                    }
                }
            }
            if (l == 0) { kcS = kcl; if (kcl == kMaxOut) doneS = 1; }
        }
        __syncthreads();                               // B3
        kc = kcS;
        if (doneS) break;
    }

    // ---- epilogue: parallel output ----
    int kcf = kcS;
    if (tid < kMaxOut) {
        if (tid < kcf) {
            int idx = kidxL[tid];
            ((float4*)out)[b * kMaxOut + tid] = kboxL[tid];
            out[kB * kMaxOut * 4 + b * kMaxOut + tid] =
                (float)labels[(size_t)b * kN + idx];
            out[kB * kMaxOut * 5 + b * kMaxOut + tid] =
                scores[(size_t)b * kN + idx];
        } else {
            ((float4*)out)[b * kMaxOut + tid] = make_float4(0.f, 0.f, 0.f, 0.f);
            out[kB * kMaxOut * 4 + b * kMaxOut + tid] = -1.0f;
            out[kB * kMaxOut * 5 + b * kMaxOut + tid] = 0.0f;
        }
    }
}

extern "C" void kernel_launch(void* const* d_in, const int* in_sizes, int n_in,
                              void* d_out, int out_size, void* d_ws, size_t ws_size,
                              hipStream_t stream)
{
    const float* preds = (const float*)d_in[0];
    const float* anchors = (const float*)d_in[1];
    float* out = (float*)d_out;

    char* ws = (char*)d_ws;
    float4* boxes = (float4*)ws;                                   // 8.60 MB
    float* scores = (float*)(ws + (size_t)kB * kN * 16);           // 2.15 MB
    int* labels = (int*)(ws + (size_t)kB * kN * 20);               // 2.15 MB
    unsigned long long* keys =
        (unsigned long long*)(ws + (size_t)kB * kN * 24);          // 64*16384*8 = 8.39 MB
    unsigned long long* keysM =
        (unsigned long long*)(ws + (size_t)kB * kN * 24 + (size_t)kB * 16384 * 8); // 4.19 MB
    unsigned long long* keys2 = keysM + (size_t)kB * kMain;        // 64*8704*8 = 4.46 MB

    decode2_k<<<(kB * kN) / 64, 256, 0, stream>>>(preds, anchors, boxes, scores, labels, keys);
    sortL_k<<<kB * 4, 512, 0, stream>>>(keys);
    lm4_k<<<kB * 2, 512, 0, stream>>>(keys);
    lm8f_k<<<kB * 2, 512, 0, stream>>>(keys, keysM);
    mergeT_k<<<kB, 512, 0, stream>>>(keysM, keys, keys2);
    nms_k<<<kB, 512, 0, stream>>>(boxes, scores, labels, keys2, out);
}

// Round 3
// 509.322 us; speedup vs baseline: 1.1094x; 1.1094x over previous
//
#include <hip/hip_runtime.h>

namespace {
constexpr int kB = 64;
constexpr int kN = 8400;
constexpr int kMain = 8192;          // bitonic-sorted main segment per image
constexpr int kTail = kN - kMain;    // 208, sorted in-LDS inside nms
constexpr int kReg = 64;
constexpr int kCls = 80;
constexpr int kStride = kReg + kCls; // 144
constexpr int kMaxOut = 100;
constexpr float kScoreTh = 0.3f;
constexpr float kIouTh = 0.5f;
}

// ---------------------------------------------------------------------------
// Stage 1: coalesced decode (verified absmax 0.0). UNCHANGED from round 1.
// ---------------------------------------------------------------------------
__global__ __launch_bounds__(256) void decode2_k(
    const float* __restrict__ preds,
    const float* __restrict__ anchors,
    float4* __restrict__ boxes,
    float* __restrict__ scores,
    int* __restrict__ labels,
    unsigned long long* __restrict__ keys)
{
    __shared__ float lds[64 * 148];
    const int tid = threadIdx.x;
    const size_t gbase = (size_t)blockIdx.x * 64;

    const float4* src = (const float4*)(preds + gbase * kStride);
    float4* l4 = (float4*)lds;
#pragma unroll
    for (int k = 0; k < 9; ++k) {
        int i = tid + k * 256;
        int row = i / 36, col = i - row * 36;
        l4[row * 37 + col] = src[i];
    }
    __syncthreads();

    const int a = tid >> 2, s = tid & 3;
    const float* rowp = lds + a * 148;

    float x[16];
    const float4* q = (const float4*)(rowp + s * 16);
#pragma unroll
    for (int j = 0; j < 4; ++j) ((float4*)x)[j] = q[j];
    float m = x[0];
#pragma unroll
    for (int j = 1; j < 16; ++j) m = fmaxf(m, x[j]);
    float se = 0.f, we = 0.f;
#pragma unroll
    for (int j = 0; j < 16; ++j) {
        float t = expf(x[j] - m);
        se += t;
        we += t * (float)j;
    }
    float d = we / se;

    const float4* cl = (const float4*)(rowp + kReg + s * 20);
    float bv = -3e38f; int bi = 0;
#pragma unroll
    for (int c = 0; c < 5; ++c) {
        float4 v = cl[c];
        int cb = s * 20 + 4 * c;
        if (v.x > bv) { bv = v.x; bi = cb; }
        if (v.y > bv) { bv = v.y; bi = cb + 1; }
        if (v.z > bv) { bv = v.z; bi = cb + 2; }
        if (v.w > bv) { bv = v.w; bi = cb + 3; }
    }

    const int lane = tid & 63;
    const int base = lane & ~3;
    float d0 = __shfl(d, base + 0, 64);
    float d1 = __shfl(d, base + 1, 64);
    float d2 = __shfl(d, base + 2, 64);
    float d3 = __shfl(d, base + 3, 64);
    float v1 = __shfl(bv, base + 1, 64); int i1 = __shfl(bi, base + 1, 64);
    float v2 = __shfl(bv, base + 2, 64); int i2 = __shfl(bi, base + 2, 64);
    float v3 = __shfl(bv, base + 3, 64); int i3 = __shfl(bi, base + 3, 64);

    if (s == 0) {
        float best = bv; int bl = bi;
        if (v1 > best) { best = v1; bl = i1; }
        if (v2 > best) { best = v2; bl = i2; }
        if (v3 > best) { best = v3; bl = i3; }

        size_t gi = gbase + a;
        int bimg = (int)(gi / kN);
        int n = (int)(gi - (size_t)bimg * kN);
        float4 av = ((const float4*)anchors)[n];
        float ah0 = av.z - av.x, ah1 = av.w - av.y;
        float c0 = (av.x + av.z) * 0.5f, c1 = (av.y + av.w) * 0.5f;
        float bc0 = (d2 - d0) * 0.5f * ah0 + c0;
        float bc1 = (d3 - d1) * 0.5f * ah1 + c1;
        float bh0 = (d2 + d0) * ah0;
        float bh1 = (d3 + d1) * ah1;
        boxes[gi] = make_float4(bc0 - bh0 * 0.5f, bc1 - bh1 * 0.5f,
                                bc0 + bh0 * 0.5f, bc1 + bh1 * 0.5f);
        scores[gi] = best;
        labels[gi] = bl;

        unsigned long long kkey = ~0ULL;
        if (best > kScoreTh) {
            unsigned u = __float_as_uint(best);
            unsigned o = u ^ ((u & 0x80000000u) ? 0xFFFFFFFFu : 0x80000000u);
            kkey = ((unsigned long long)(~o) << 32) | (unsigned)n;
        }
        keys[((size_t)bimg << 14) + n] = kkey;
    }
}

// ---------------------------------------------------------------------------
// Sort pipeline — SAME comparator network as round 1 (desc = (global_i &
// size) != 0, sizes 2..8192), now register-resident: strides 1-2 (sortL) /
// 1-4 (lm2) in registers, strides up to 128/256 via __shfl_xor in-wave,
// only strides >= 256/512 touch LDS (6 passes vs 66 in sortL, 3 vs 12 in
// lm2). LDS scratch layout lk[k*512+tid] keeps exchanges stride-1 (2-way
// bank aliasing = free). min/max-keep is equivalent to the swap form
// (ties only among ~0 pads -> identical results), so output is bit-identical.
// ---------------------------------------------------------------------------
__global__ __launch_bounds__(512) void sortL_k(unsigned long long* __restrict__ keys)
{
    __shared__ unsigned long long lk[2048];          // 16 KB
    const int tid = threadIdx.x;
    const int img = blockIdx.x >> 2, seg = blockIdx.x & 3;
    const int gofs = seg << 11;
    unsigned long long* base = keys + ((size_t)img << 14) + gofs;

    unsigned long long r[4];
    const int e0 = tid << 2;
#pragma unroll
    for (int k = 0; k < 4; ++k) r[k] = base[e0 + k];

    // stride-2 pass: pairs (k, k+2)
    auto ce2 = [&](int size) {
#pragma unroll
        for (int k = 0; k < 2; ++k) {
            bool desc = (((gofs + e0 + k) & size) != 0);
            unsigned long long a = r[k], c = r[k + 2];
            bool sw = desc ? (c > a) : (a > c);
            if (sw) { r[k] = c; r[k + 2] = a; }
        }
    };
    // stride-1 pass: pairs (k, k+1), k even
    auto ce1 = [&](int size) {
#pragma unroll
        for (int k = 0; k < 4; k += 2) {
            bool desc = (((gofs + e0 + k) & size) != 0);
            unsigned long long a = r[k], c = r[k + 1];
            bool sw = desc ? (c > a) : (a > c);
            if (sw) { r[k] = c; r[k + 1] = a; }
        }
    };

    ce1(2);                                           // size = 2
    for (int size = 4; size <= 2048; size <<= 1) {
        for (int stride = size >> 1; stride >= 4; stride >>= 1) {
            if (stride >= 256) {                      // cross-wave: LDS
                __syncthreads();
#pragma unroll
                for (int k = 0; k < 4; ++k) lk[k * 512 + tid] = r[k];
                __syncthreads();
                const int pt = tid ^ (stride >> 2);
#pragma unroll
                for (int k = 0; k < 4; ++k) {
                    unsigned long long o = lk[k * 512 + pt];
                    int e = e0 + k;
                    bool keep_min = (((e & stride) == 0) !=
                                     (((gofs + e) & size) != 0));
                    r[k] = keep_min ? (r[k] < o ? r[k] : o)
                                    : (r[k] > o ? r[k] : o);
                }
            } else {                                  // in-wave: shuffle
                const int d = stride >> 2;
#pragma unroll
                for (int k = 0; k < 4; ++k) {
                    unsigned long long o = __shfl_xor(r[k], d, 64);
                    int e = e0 + k;
                    bool keep_min = (((e & stride) == 0) !=
                                     (((gofs + e) & size) != 0));
                    r[k] = keep_min ? (r[k] < o ? r[k] : o)
                                    : (r[k] > o ? r[k] : o);
                }
            }
        }
        ce2(size);
        ce1(size);
    }
#pragma unroll
    for (int k = 0; k < 4; ++k) base[e0 + k] = r[k];
}

// size=8192, stride=4096: pairs (n, n+4096), ascending. UNCHANGED.
__global__ __launch_bounds__(256) void gce_k(unsigned long long* __restrict__ keys)
{
    int tg = blockIdx.x * 256 + threadIdx.x;         // 64 img * 4096 pairs
    int img = tg >> 12;
    int n = tg & 4095;
    unsigned long long* base = keys + ((size_t)img << 14);
    unsigned long long a = base[n], c = base[n + 4096];
    if (a > c) { base[n] = c; base[n + 4096] = a; }
}

template <int SIZE>
__global__ __launch_bounds__(512) void lm2_k(unsigned long long* __restrict__ keys)
{
    __shared__ unsigned long long lk[4096];          // 32 KB
    const int tid = threadIdx.x;
    const int img = blockIdx.x >> 1, half = blockIdx.x & 1;
    const int gofs = half << 12;
    unsigned long long* base = keys + ((size_t)img << 14) + gofs;
    const bool desc = (gofs & SIZE) != 0;            // uniform per block

    unsigned long long r[8];
    const int e0 = tid << 3;
#pragma unroll
    for (int k = 0; k < 8; ++k) r[k] = base[e0 + k];

    // strides 2048, 1024, 512: LDS exchange
    for (int stride = 2048; stride >= 512; stride >>= 1) {
        __syncthreads();
#pragma unroll
        for (int k = 0; k < 8; ++k) lk[k * 512 + tid] = r[k];
        __syncthreads();
        const int pt = tid ^ (stride >> 3);
#pragma unroll
        for (int k = 0; k < 8; ++k) {
            unsigned long long o = lk[k * 512 + pt];
            bool keep_min = ((((e0 + k) & stride) == 0) != desc);
            r[k] = keep_min ? (r[k] < o ? r[k] : o) : (r[k] > o ? r[k] : o);
        }
    }
    // strides 256..8: in-wave shuffle
    for (int stride = 256; stride >= 8; stride >>= 1) {
        const int d = stride >> 3;
#pragma unroll
        for (int k = 0; k < 8; ++k) {
            unsigned long long o = __shfl_xor(r[k], d, 64);
            bool keep_min = ((((e0 + k) & stride) == 0) != desc);
            r[k] = keep_min ? (r[k] < o ? r[k] : o) : (r[k] > o ? r[k] : o);
        }
    }
    // strides 4, 2, 1: registers (compile-time indices)
    auto ce = [&](int i, int j) {
        unsigned long long a = r[i], c = r[j];
        bool sw = desc ? (c > a) : (a > c);
        if (sw) { r[i] = c; r[j] = a; }
    };
    ce(0, 4); ce(1, 5); ce(2, 6); ce(3, 7);          // stride 4
    ce(0, 2); ce(1, 3); ce(4, 6); ce(5, 7);          // stride 2
    ce(0, 1); ce(2, 3); ce(4, 5); ce(6, 7);          // stride 1
#pragma unroll
    for (int k = 0; k < 8; ++k) base[e0 + k] = r[k];
}

// ---------------------------------------------------------------------------
// Stage 2: sorted greedy NMS with on-the-fly 2-way merge. UNCHANGED from
// round 1 (the verified 512.8 us version).
// ---------------------------------------------------------------------------
__device__ __forceinline__ unsigned long long getB_(
    const unsigned long long* tailL, int p1, int x)
{
    int t = p1 + x;
    return (t < 256) ? tailL[t] : ~0ULL;
}

__global__ __launch_bounds__(256) void nms_k(
    const float4* __restrict__ boxes,
    const float* __restrict__ scores,
    const int* __restrict__ labels,
    const unsigned long long* __restrict__ keys,
    float* __restrict__ out)
{
    __shared__ unsigned long long tailL[256];
    __shared__ unsigned long long aw[512];
    __shared__ float4 sbox[256];
    __shared__ float  sar[256];
    __shared__ int    sidx[256];
    __shared__ float4 kboxL[kMaxOut];
    __shared__ float  kareaL[kMaxOut];
    __shared__ int    kidxL[kMaxOut];
    __shared__ unsigned long long ballS[4];
    __shared__ int p0S, p1S, kcS, doneS, stopS;

    const int b = blockIdx.x, tid = threadIdx.x;
    const unsigned long long* mainA = keys + ((size_t)b << 14);
    const float4* bx = boxes + (size_t)b * kN;

    if (tid == 0) { p0S = 0; p1S = 0; kcS = 0; doneS = 0; }

    // ---- sort the 208-key tail (pad to 256) in LDS, ascending bitonic ----
    tailL[tid] = (tid < kTail) ? mainA[kMain + tid] : ~0ULL;
    __syncthreads();
    for (int size = 2; size <= 256; size <<= 1) {
        for (int stride = size >> 1; stride > 0; stride >>= 1) {
            if (tid < 128) {
                int i = ((tid & ~(stride - 1)) << 1) | (tid & (stride - 1));
                int j = i + stride;
                bool desc = (i & size) != 0;
                unsigned long long a = tailL[i], c = tailL[j];
                bool sw = desc ? (c > a) : (a > c);
                if (sw) { tailL[i] = c; tailL[j] = a; }
            }
            __syncthreads();
        }
    }

    int kc = 0;
    for (int c = 0; c < 33; ++c) {
        int p0 = p0S, p1 = p1S;          // synced by previous barrier
        aw[tid]       = (p0 + tid       < kMain) ? mainA[p0 + tid]       : ~0ULL;
        aw[tid + 256] = (p0 + tid + 256 < kMain) ? mainA[p0 + tid + 256] : ~0ULL;
        __syncthreads();                  // B1: window visible

        // ---- merge-path: thread t produces merged element at diagonal t ----
        int d = tid;
        int lo = 0, hi = d;
        while (lo < hi) {
            int mid = (lo + hi) >> 1;     // mid < d
            bool c2 = getB_(tailL, p1, d - mid - 1) < aw[mid];
            if (c2) hi = mid; else lo = mid + 1;
        }
        unsigned long long av = aw[lo];
        unsigned long long bv = getB_(tailL, p1, d - lo);
        unsigned long long key = (av <= bv) ? av : bv;   // A-first ties (pads only)

        bool alive = (key != ~0ULL);
        int idx = alive ? (int)(key & 0xFFFFFFFFULL) : 0;
        float4 cb = bx[idx];
        float ac = (cb.z - cb.x) * (cb.w - cb.y);

        // ---- pre-test vs keeps from previous chunks ----
        if (alive) {
            for (int k = 0; k < kc; ++k) {
                float4 kb = kboxL[k];
                float t0 = fmaxf(kb.x, cb.x), t1 = fmaxf(kb.y, cb.y);
                float b0 = fminf(kb.z, cb.z), b1 = fminf(kb.w, cb.w);
                float inter = fmaxf(b0 - t0, 0.f) * fmaxf(b1 - t1, 0.f);
                float iou = inter / (kareaL[k] + ac - inter + 1e-9f);
                if (iou > kIouTh) { alive = false; break; }
            }
        }
        sbox[tid] = cb; sar[tid] = ac; sidx[tid] = idx;
        unsigned long long mm = __ballot((int)alive);
        if ((tid & 63) == 0) ballS[tid >> 6] = mm;
        if (tid == 0) {
            stopS = (key == ~0ULL);       // diagonal-0 key == min remaining
            // advance pointers: merge-path at diagonal 256
            int lo2 = 0, hi2 = 256;
            while (lo2 < hi2) {
                int mid = (lo2 + hi2) >> 1;
                bool c2 = getB_(tailL, p1, 255 - mid) < aw[mid];
                if (c2) hi2 = mid; else lo2 = mid + 1;
            }
            p0S = p0 + lo2; p1S = p1 + (256 - lo2);
        }
        __syncthreads();                  // B2: sbox/ball/stop/pointers visible
        if (stopS) break;

        // ---- wave0-only in-chunk greedy resolve (no block barriers) ----
        if (tid < 64) {
            const int lane = tid;
            unsigned a4 = 0;
#pragma unroll
            for (int j = 0; j < 4; ++j)
                a4 |= (unsigned)((ballS[j] >> lane) & 1ULL) << j;
            int kcl = kc;
            while (true) {
                int jF = -1, lF = 0;
#pragma unroll
                for (int j = 0; j < 4; ++j) {
                    if (jF < 0) {
                        unsigned long long m2 = __ballot((int)((a4 >> j) & 1u));
                        if (m2) { jF = j; lF = __ffsll((unsigned long long)m2) - 1; }
                    }
                }
                if (jF < 0) break;
                int cs = (jF << 6) + lF;
                float4 kb = sbox[cs];
                float kar = sar[cs];
                if (lane == 0) {
                    kboxL[kcl] = kb; kareaL[kcl] = kar; kidxL[kcl] = sidx[cs];
                }
                if (lane == lF) a4 &= ~(1u << jF);
                ++kcl;
                if (kcl == kMaxOut) break;
#pragma unroll
                for (int j = 0; j < 4; ++j) {
                    if ((a4 >> j) & 1u) {
                        float4 cb2 = sbox[lane + (j << 6)];
                        float ac2 = sar[lane + (j << 6)];
                        float t0 = fmaxf(kb.x, cb2.x), t1 = fmaxf(kb.y, cb2.y);
                        float b0 = fminf(kb.z, cb2.z), b1 = fminf(kb.w, cb2.w);
                        float inter = fmaxf(b0 - t0, 0.f) * fmaxf(b1 - t1, 0.f);
                        float iou = inter / (kar + ac2 - inter + 1e-9f);
                        if (iou > kIouTh) a4 &= ~(1u << j);
                    }
                }
            }
            if (lane == 0) { kcS = kcl; if (kcl == kMaxOut) doneS = 1; }
        }
        __syncthreads();                  // B3: keeps visible
        kc = kcS;
        if (doneS) break;
    }

    // ---- epilogue: parallel output ----
    int kcf = kcS;
    if (tid < kMaxOut) {
        if (tid < kcf) {
            int idx = kidxL[tid];
            ((float4*)out)[b * kMaxOut + tid] = kboxL[tid];
            out[kB * kMaxOut * 4 + b * kMaxOut + tid] =
                (float)labels[(size_t)b * kN + idx];
            out[kB * kMaxOut * 5 + b * kMaxOut + tid] =
                scores[(size_t)b * kN + idx];
        } else {
            ((float4*)out)[b * kMaxOut + tid] = make_float4(0.f, 0.f, 0.f, 0.f);
            out[kB * kMaxOut * 4 + b * kMaxOut + tid] = -1.0f;
            out[kB * kMaxOut * 5 + b * kMaxOut + tid] = 0.0f;
        }
    }
}

extern "C" void kernel_launch(void* const* d_in, const int* in_sizes, int n_in,
                              void* d_out, int out_size, void* d_ws, size_t ws_size,
                              hipStream_t stream)
{
    const float* preds = (const float*)d_in[0];
    const float* anchors = (const float*)d_in[1];
    float* out = (float*)d_out;

    char* ws = (char*)d_ws;
    float4* boxes = (float4*)ws;                                   // 8.60 MB
    float* scores = (float*)(ws + (size_t)kB * kN * 16);           // 2.15 MB
    int* labels = (int*)(ws + (size_t)kB * kN * 20);               // 2.15 MB
    unsigned long long* keys =
        (unsigned long long*)(ws + (size_t)kB * kN * 24);          // 64*16384*8

    decode2_k<<<(kB * kN) / 64, 256, 0, stream>>>(preds, anchors, boxes, scores, labels, keys);
    sortL_k<<<kB * 4, 512, 0, stream>>>(keys);
    lm2_k<4096><<<kB * 2, 512, 0, stream>>>(keys);
    gce_k<<<(kB * 4096) / 256, 256, 0, stream>>>(keys);
    lm2_k<8192><<<kB * 2, 512, 0, stream>>>(keys);
    nms_k<<<kB, 256, 0, stream>>>(boxes, scores, labels, keys, out);
}

// Round 4
// 508.357 us; speedup vs baseline: 1.1115x; 1.0019x over previous
//
#include <hip/hip_runtime.h>

namespace {
constexpr int kB = 64;
constexpr int kN = 8400;
constexpr int kMain = 8192;          // bitonic-sorted main segment per image
constexpr int kTail = kN - kMain;    // 208, sorted in-LDS inside snms
constexpr int kReg = 64;
constexpr int kCls = 80;
constexpr int kStride = kReg + kCls; // 144
constexpr int kMaxOut = 100;
constexpr float kScoreTh = 0.3f;
constexpr float kIouTh = 0.5f;
}

// ---------------------------------------------------------------------------
// Stage 1: coalesced decode (verified absmax 0.0). UNCHANGED.
// ---------------------------------------------------------------------------
__global__ __launch_bounds__(256) void decode2_k(
    const float* __restrict__ preds,
    const float* __restrict__ anchors,
    float4* __restrict__ boxes,
    float* __restrict__ scores,
    int* __restrict__ labels,
    unsigned long long* __restrict__ keys)
{
    __shared__ float lds[64 * 148];
    const int tid = threadIdx.x;
    const size_t gbase = (size_t)blockIdx.x * 64;

    const float4* src = (const float4*)(preds + gbase * kStride);
    float4* l4 = (float4*)lds;
#pragma unroll
    for (int k = 0; k < 9; ++k) {
        int i = tid + k * 256;
        int row = i / 36, col = i - row * 36;
        l4[row * 37 + col] = src[i];
    }
    __syncthreads();

    const int a = tid >> 2, s = tid & 3;
    const float* rowp = lds + a * 148;

    float x[16];
    const float4* q = (const float4*)(rowp + s * 16);
#pragma unroll
    for (int j = 0; j < 4; ++j) ((float4*)x)[j] = q[j];
    float m = x[0];
#pragma unroll
    for (int j = 1; j < 16; ++j) m = fmaxf(m, x[j]);
    float se = 0.f, we = 0.f;
#pragma unroll
    for (int j = 0; j < 16; ++j) {
        float t = expf(x[j] - m);
        se += t;
        we += t * (float)j;
    }
    float d = we / se;

    const float4* cl = (const float4*)(rowp + kReg + s * 20);
    float bv = -3e38f; int bi = 0;
#pragma unroll
    for (int c = 0; c < 5; ++c) {
        float4 v = cl[c];
        int cb = s * 20 + 4 * c;
        if (v.x > bv) { bv = v.x; bi = cb; }
        if (v.y > bv) { bv = v.y; bi = cb + 1; }
        if (v.z > bv) { bv = v.z; bi = cb + 2; }
        if (v.w > bv) { bv = v.w; bi = cb + 3; }
    }

    const int lane = tid & 63;
    const int base = lane & ~3;
    float d0 = __shfl(d, base + 0, 64);
    float d1 = __shfl(d, base + 1, 64);
    float d2 = __shfl(d, base + 2, 64);
    float d3 = __shfl(d, base + 3, 64);
    float v1 = __shfl(bv, base + 1, 64); int i1 = __shfl(bi, base + 1, 64);
    float v2 = __shfl(bv, base + 2, 64); int i2 = __shfl(bi, base + 2, 64);
    float v3 = __shfl(bv, base + 3, 64); int i3 = __shfl(bi, base + 3, 64);

    if (s == 0) {
        float best = bv; int bl = bi;
        if (v1 > best) { best = v1; bl = i1; }
        if (v2 > best) { best = v2; bl = i2; }
        if (v3 > best) { best = v3; bl = i3; }

        size_t gi = gbase + a;
        int bimg = (int)(gi / kN);
        int n = (int)(gi - (size_t)bimg * kN);
        float4 av = ((const float4*)anchors)[n];
        float ah0 = av.z - av.x, ah1 = av.w - av.y;
        float c0 = (av.x + av.z) * 0.5f, c1 = (av.y + av.w) * 0.5f;
        float bc0 = (d2 - d0) * 0.5f * ah0 + c0;
        float bc1 = (d3 - d1) * 0.5f * ah1 + c1;
        float bh0 = (d2 + d0) * ah0;
        float bh1 = (d3 + d1) * ah1;
        boxes[gi] = make_float4(bc0 - bh0 * 0.5f, bc1 - bh1 * 0.5f,
                                bc0 + bh0 * 0.5f, bc1 + bh1 * 0.5f);
        scores[gi] = best;
        labels[gi] = bl;

        unsigned long long kkey = ~0ULL;
        if (best > kScoreTh) {
            unsigned u = __float_as_uint(best);
            unsigned o = u ^ ((u & 0x80000000u) ? 0xFFFFFFFFu : 0x80000000u);
            kkey = ((unsigned long long)(~o) << 32) | (unsigned)n;
        }
        keys[((size_t)bimg << 14) + n] = kkey;
    }
}

// ---------------------------------------------------------------------------
// sortL: sizes 2..2048 of the verified network (desc = (global_i & size)),
// register-resident. UNCHANGED from round 3 (verified absmax 0.0).
// ---------------------------------------------------------------------------
__global__ __launch_bounds__(512) void sortL_k(unsigned long long* __restrict__ keys)
{
    __shared__ unsigned long long lk[2048];          // 16 KB
    const int tid = threadIdx.x;
    const int img = blockIdx.x >> 2, seg = blockIdx.x & 3;
    const int gofs = seg << 11;
    unsigned long long* base = keys + ((size_t)img << 14) + gofs;

    unsigned long long r[4];
    const int e0 = tid << 2;
#pragma unroll
    for (int k = 0; k < 4; ++k) r[k] = base[e0 + k];

    auto ce2 = [&](int size) {
#pragma unroll
        for (int k = 0; k < 2; ++k) {
            bool desc = (((gofs + e0 + k) & size) != 0);
            unsigned long long a = r[k], c = r[k + 2];
            bool sw = desc ? (c > a) : (a > c);
            if (sw) { r[k] = c; r[k + 2] = a; }
        }
    };
    auto ce1 = [&](int size) {
#pragma unroll
        for (int k = 0; k < 4; k += 2) {
            bool desc = (((gofs + e0 + k) & size) != 0);
            unsigned long long a = r[k], c = r[k + 1];
            bool sw = desc ? (c > a) : (a > c);
            if (sw) { r[k] = c; r[k + 1] = a; }
        }
    };

    ce1(2);                                           // size = 2
    for (int size = 4; size <= 2048; size <<= 1) {
        for (int stride = size >> 1; stride >= 4; stride >>= 1) {
            if (stride >= 256) {                      // cross-wave: LDS
                __syncthreads();
#pragma unroll
                for (int k = 0; k < 4; ++k) lk[k * 512 + tid] = r[k];
                __syncthreads();
                const int pt = tid ^ (stride >> 2);
#pragma unroll
                for (int k = 0; k < 4; ++k) {
                    unsigned long long o = lk[k * 512 + pt];
                    int e = e0 + k;
                    bool keep_min = (((e & stride) == 0) !=
                                     (((gofs + e) & size) != 0));
                    r[k] = keep_min ? (r[k] < o ? r[k] : o)
                                    : (r[k] > o ? r[k] : o);
                }
            } else {                                  // in-wave: shuffle
                const int d = stride >> 2;
#pragma unroll
                for (int k = 0; k < 4; ++k) {
                    unsigned long long o = __shfl_xor(r[k], d, 64);
                    int e = e0 + k;
                    bool keep_min = (((e & stride) == 0) !=
                                     (((gofs + e) & size) != 0));
                    r[k] = keep_min ? (r[k] < o ? r[k] : o)
                                    : (r[k] > o ? r[k] : o);
                }
            }
        }
        ce2(size);
        ce1(size);
    }
#pragma unroll
    for (int k = 0; k < 4; ++k) base[e0 + k] = r[k];
}

// ---------------------------------------------------------------------------
// snms: fused {sizes 4096+8192 of the bitonic network} + {tail sort} +
// {sorted greedy NMS}. One block per image, 512 threads, 16 keys/thread.
// Sorted main segment stays resident in lk[8192] (64 KB LDS); the NMS
// merge loop reads it directly (no global key re-read). Comparator pairs,
// directions and min/max-keep are identical to the verified pipeline, so
// the stream is bit-identical; NMS logic is verbatim round-1.
// ---------------------------------------------------------------------------
__device__ __forceinline__ unsigned long long getB_(
    const unsigned long long* tailL, int p1, int x)
{
    int t = p1 + x;
    return (t < 256) ? tailL[t] : ~0ULL;
}

__global__ __launch_bounds__(512) void snms_k(
    const float4* __restrict__ boxes,
    const float* __restrict__ scores,
    const int* __restrict__ labels,
    const unsigned long long* __restrict__ keys,
    float* __restrict__ out)
{
    __shared__ unsigned long long lk[8192];          // 64 KB
    __shared__ unsigned long long tailL[256];
    __shared__ float4 sbox[256];
    __shared__ float  sar[256];
    __shared__ int    sidx[256];
    __shared__ float4 kboxL[kMaxOut];
    __shared__ float  kareaL[kMaxOut];
    __shared__ int    kidxL[kMaxOut];
    __shared__ unsigned long long ballS[4];
    __shared__ int p0S, p1S, kcS, doneS, stopS;

    const int b = blockIdx.x, tid = threadIdx.x;
    const unsigned long long* mainG = keys + ((size_t)b << 14);
    const float4* bx = boxes + (size_t)b * kN;

    // ---- finish the bitonic network: sizes 4096, 8192 ----
    unsigned long long r[16];
    const int e0 = tid << 4;
#pragma unroll
    for (int k = 0; k < 16; ++k) r[k] = mainG[e0 + k];

    for (int size = 4096; size <= 8192; size <<= 1) {
        const bool desc = (e0 & size) != 0;          // size=8192 -> false (asc)
        for (int stride = size >> 1; stride >= 1024; stride >>= 1) {
            __syncthreads();                          // prev pass reads done
#pragma unroll
            for (int k = 0; k < 16; ++k) lk[k * 512 + tid] = r[k];
            __syncthreads();
            const int pt = tid ^ (stride >> 4);
            const bool keep_min = ((e0 & stride) == 0) != desc;
#pragma unroll
            for (int k = 0; k < 16; ++k) {
                unsigned long long o = lk[k * 512 + pt];
                r[k] = keep_min ? (r[k] < o ? r[k] : o)
                                : (r[k] > o ? r[k] : o);
            }
        }
        for (int stride = 512; stride >= 16; stride >>= 1) {
            const int d = stride >> 4;
            const bool keep_min = ((e0 & stride) == 0) != desc;
#pragma unroll
            for (int k = 0; k < 16; ++k) {
                unsigned long long o = __shfl_xor(r[k], d, 64);
                r[k] = keep_min ? (r[k] < o ? r[k] : o)
                                : (r[k] > o ? r[k] : o);
            }
        }
        auto ce = [&](int i, int j) {
            unsigned long long a = r[i], c = r[j];
            bool sw = desc ? (c > a) : (a > c);
            if (sw) { r[i] = c; r[j] = a; }
        };
        // stride 8
        ce(0,8); ce(1,9); ce(2,10); ce(3,11); ce(4,12); ce(5,13); ce(6,14); ce(7,15);
        // stride 4
        ce(0,4); ce(1,5); ce(2,6); ce(3,7); ce(8,12); ce(9,13); ce(10,14); ce(11,15);
        // stride 2
        ce(0,2); ce(1,3); ce(4,6); ce(5,7); ce(8,10); ce(9,11); ce(12,14); ce(13,15);
        // stride 1
        ce(0,1); ce(2,3); ce(4,5); ce(6,7); ce(8,9); ce(10,11); ce(12,13); ce(14,15);
    }
    __syncthreads();        // last LDS-pass reads complete before re-layout
#pragma unroll
    for (int k = 0; k < 16; ++k) lk[e0 + k] = r[k];  // sorted main, std layout

    if (tid == 0) { p0S = 0; p1S = 0; kcS = 0; doneS = 0; }
    if (tid < 256)
        tailL[tid] = (tid < kTail) ? mainG[kMain + tid] : ~0ULL;
    __syncthreads();        // lk + tailL + scalars visible

    // ---- sort the 208-key tail (pad to 256), ascending bitonic ----
    for (int size = 2; size <= 256; size <<= 1) {
        for (int stride = size >> 1; stride > 0; stride >>= 1) {
            if (tid < 128) {
                int i = ((tid & ~(stride - 1)) << 1) | (tid & (stride - 1));
                int j = i + stride;
                bool desc = (i & size) != 0;
                unsigned long long a = tailL[i], c = tailL[j];
                bool sw = desc ? (c > a) : (a > c);
                if (sw) { tailL[i] = c; tailL[j] = a; }
            }
            __syncthreads();
        }
    }

    int kc = 0;
    for (int c = 0; c < 33; ++c) {
        int p0 = p0S, p1 = p1S;          // visible via prior barrier
        unsigned long long key = ~0ULL;
        if (tid < 256) {
            // merge-path: thread t produces merged element at diagonal t
            int dd = tid, lo = 0, hi = dd;
            while (lo < hi) {
                int mid = (lo + hi) >> 1;             // mid < dd
                unsigned long long amid =
                    (p0 + mid < kMain) ? lk[p0 + mid] : ~0ULL;
                if (getB_(tailL, p1, dd - mid - 1) < amid) hi = mid;
                else lo = mid + 1;
            }
            unsigned long long av = (p0 + lo < kMain) ? lk[p0 + lo] : ~0ULL;
            unsigned long long bv = getB_(tailL, p1, dd - lo);
            key = (av <= bv) ? av : bv;               // A-first ties (pads only)

            bool alive = (key != ~0ULL);
            int idx = alive ? (int)(key & 0xFFFFFFFFULL) : 0;
            float4 cb = bx[idx];
            float ac = (cb.z - cb.x) * (cb.w - cb.y);

            if (alive) {
                for (int k = 0; k < kc; ++k) {
                    float4 kb = kboxL[k];
                    float t0 = fmaxf(kb.x, cb.x), t1 = fmaxf(kb.y, cb.y);
                    float b0 = fminf(kb.z, cb.z), b1 = fminf(kb.w, cb.w);
                    float inter = fmaxf(b0 - t0, 0.f) * fmaxf(b1 - t1, 0.f);
                    float iou = inter / (kareaL[k] + ac - inter + 1e-9f);
                    if (iou > kIouTh) { alive = false; break; }
                }
            }
            sbox[tid] = cb; sar[tid] = ac; sidx[tid] = idx;
            unsigned long long mm = __ballot((int)alive);
            if ((tid & 63) == 0) ballS[tid >> 6] = mm;
        }
        if (tid == 0) {
            stopS = (key == ~0ULL);       // diagonal-0 key == min remaining
            int lo2 = 0, hi2 = 256;
            while (lo2 < hi2) {
                int mid = (lo2 + hi2) >> 1;
                unsigned long long amid =
                    (p0 + mid < kMain) ? lk[p0 + mid] : ~0ULL;
                if (getB_(tailL, p1, 255 - mid) < amid) hi2 = mid;
                else lo2 = mid + 1;
            }
            p0S = p0 + lo2; p1S = p1 + (256 - lo2);
        }
        __syncthreads();                  // B2: sbox/ball/stop/pointers visible
        if (stopS) break;

        // ---- wave0-only in-chunk greedy resolve (no block barriers) ----
        if (tid < 64) {
            const int lane = tid;
            unsigned a4 = 0;
#pragma unroll
            for (int j = 0; j < 4; ++j)
                a4 |= (unsigned)((ballS[j] >> lane) & 1ULL) << j;
            int kcl = kc;
            while (true) {
                int jF = -1, lF = 0;
#pragma unroll
                for (int j = 0; j < 4; ++j) {
                    if (jF < 0) {
                        unsigned long long m2 = __ballot((int)((a4 >> j) & 1u));
                        if (m2) { jF = j; lF = __ffsll((unsigned long long)m2) - 1; }
                    }
                }
                if (jF < 0) break;
                int cs = (jF << 6) + lF;
                float4 kb = sbox[cs];
                float kar = sar[cs];
                if (lane == 0) {
                    kboxL[kcl] = kb; kareaL[kcl] = kar; kidxL[kcl] = sidx[cs];
                }
                if (lane == lF) a4 &= ~(1u << jF);
                ++kcl;
                if (kcl == kMaxOut) break;
#pragma unroll
                for (int j = 0; j < 4; ++j) {
                    if ((a4 >> j) & 1u) {
                        float4 cb2 = sbox[lane + (j << 6)];
                        float ac2 = sar[lane + (j << 6)];
                        float t0 = fmaxf(kb.x, cb2.x), t1 = fmaxf(kb.y, cb2.y);
                        float b0 = fminf(kb.z, cb2.z), b1 = fminf(kb.w, cb2.w);
                        float inter = fmaxf(b0 - t0, 0.f) * fmaxf(b1 - t1, 0.f);
                        float iou = inter / (kar + ac2 - inter + 1e-9f);
                        if (iou > kIouTh) a4 &= ~(1u << j);
                    }
                }
            }
            if (lane == 0) { kcS = kcl; if (kcl == kMaxOut) doneS = 1; }
        }
        __syncthreads();                  // B3: keeps visible
        kc = kcS;
        if (doneS) break;
    }

    // ---- epilogue: parallel output ----
    int kcf = kcS;
    if (tid < kMaxOut) {
        if (tid < kcf) {
            int idx = kidxL[tid];
            ((float4*)out)[b * kMaxOut + tid] = kboxL[tid];
            out[kB * kMaxOut * 4 + b * kMaxOut + tid] =
                (float)labels[(size_t)b * kN + idx];
            out[kB * kMaxOut * 5 + b * kMaxOut + tid] =
                scores[(size_t)b * kN + idx];
        } else {
            ((float4*)out)[b * kMaxOut + tid] = make_float4(0.f, 0.f, 0.f, 0.f);
            out[kB * kMaxOut * 4 + b * kMaxOut + tid] = -1.0f;
            out[kB * kMaxOut * 5 + b * kMaxOut + tid] = 0.0f;
        }
    }
}

extern "C" void kernel_launch(void* const* d_in, const int* in_sizes, int n_in,
                              void* d_out, int out_size, void* d_ws, size_t ws_size,
                              hipStream_t stream)
{
    const float* preds = (const float*)d_in[0];
    const float* anchors = (const float*)d_in[1];
    float* out = (float*)d_out;

    char* ws = (char*)d_ws;
    float4* boxes = (float4*)ws;                                   // 8.60 MB
    float* scores = (float*)(ws + (size_t)kB * kN * 16);           // 2.15 MB
    int* labels = (int*)(ws + (size_t)kB * kN * 20);               // 2.15 MB
    unsigned long long* keys =
        (unsigned long long*)(ws + (size_t)kB * kN * 24);          // 64*16384*8

    decode2_k<<<(kB * kN) / 64, 256, 0, stream>>>(preds, anchors, boxes, scores, labels, keys);
    sortL_k<<<kB * 4, 512, 0, stream>>>(keys);
    snms_k<<<kB, 512, 0, stream>>>(boxes, scores, labels, keys, out);
}